// Round 12
// baseline (845.548 us; speedup 1.0000x reference)
//
#include <hip/hip_runtime.h>
#include <hip/hip_fp16.h>

#define N_NODES 25000   // = 3125 * 8 exactly
#define E_EDGES 400000
#define KM 200     // message channels
#define RSH 224    // row stride in halfs: 200 fp16 payload | 20 fp16 x | fp32 inv_p | fp32 inv_x = 448 B

// ---------------- helpers ----------------

__device__ __forceinline__ float2 h2f(unsigned u) {
  return __half22float2(*(const __half2*)&u);
}

// ---------------- sort-by-dst (CSR build) ----------------

__global__ void hist_kernel(const int* __restrict__ edges, int* __restrict__ hist) {
  int e = blockIdx.x * blockDim.x + threadIdx.x;
  if (e < E_EDGES) atomicAdd(&hist[edges[E_EDGES + e]], 1);
}

__global__ void scan_kernel(const int* __restrict__ hist, int* __restrict__ off,
                            int* __restrict__ cursor) {
  __shared__ int sums[1024];
  const int CH = (N_NODES + 1023) / 1024;  // 25
  int tid = threadIdx.x;
  int base = tid * CH;
  int s = 0;
  for (int i = 0; i < CH; i++) {
    int idx = base + i;
    if (idx < N_NODES) s += hist[idx];
  }
  sums[tid] = s;
  __syncthreads();
  for (int d = 1; d < 1024; d <<= 1) {
    int v = (tid >= d) ? sums[tid - d] : 0;
    __syncthreads();
    sums[tid] += v;
    __syncthreads();
  }
  int run = (tid == 0) ? 0 : sums[tid - 1];
  for (int i = 0; i < CH; i++) {
    int idx = base + i;
    if (idx < N_NODES) {
      off[idx] = run;
      cursor[idx] = run;
      run += hist[idx];
    }
  }
  if (tid == 1023) off[N_NODES] = run;  // == E
}

__global__ void scatter_kernel(const int* __restrict__ edges, int* __restrict__ cursor,
                               int* __restrict__ srcS, int* __restrict__ dstS) {
  int e = blockIdx.x * blockDim.x + threadIdx.x;
  if (e < E_EDGES) {
    int s = edges[e];
    int d = edges[E_EDGES + e];
    int pos = atomicAdd(&cursor[d], 1);
    srcS[pos] = s;
    dstS[pos] = d;
  }
}

// ---------------- per-layer kernels ----------------

// prep (layer d, CIN=1): both A and B rows fp16-scaled (bound-based scales).
__global__ void __launch_bounds__(256) prep_d_kernel(
    const float* __restrict__ xin,
    const float* __restrict__ Wm1, const float* __restrict__ bm1,
    __half* __restrict__ Ah, __half* __restrict__ Bh, float* __restrict__ xr) {
  __shared__ unsigned wamaxu, wbmaxu, bmmaxu;
  int k = threadIdx.x;  // 0..255
  if (k == 0) { wamaxu = 0; wbmaxu = 0; bmmaxu = 0; }
  __syncthreads();
  float wa = 0.f, wb = 0.f, bm = 0.f;
  if (k < KM) {
    bm = bm1[k];
    wa = Wm1[k];
    wb = Wm1[KM + k];
  }
  float ma = (k < KM) ? fabsf(wa) : 0.f;
  float mb = (k < KM) ? fabsf(wb) : 0.f;
  float mm = (k < KM) ? fabsf(bm) : 0.f;
#pragma unroll
  for (int s = 1; s < 64; s <<= 1) {
    ma = fmaxf(ma, __shfl_xor(ma, s));
    mb = fmaxf(mb, __shfl_xor(mb, s));
    mm = fmaxf(mm, __shfl_xor(mm, s));
  }
  if ((k & 63) == 0) {
    atomicMax(&wamaxu, __float_as_uint(ma));
    atomicMax(&wbmaxu, __float_as_uint(mb));
    atomicMax(&bmmaxu, __float_as_uint(mm));
  }
  __syncthreads();
  float wamax = __uint_as_float(wamaxu);
  float wbmax = __uint_as_float(wbmaxu);
  float bmmax = __uint_as_float(bmmaxu);
  int n0 = blockIdx.x * 8;
  for (int i = 0; i < 8; i++) {
    int n = n0 + i;
    float xv = xin[n];
    float aBound = fmaxf(bmmax + fabsf(xv) * wamax, 1e-30f);
    float bBound = fmaxf(fabsf(xv) * wbmax, 1e-30f);
    float xBound = fmaxf(fabsf(xv), 1e-30f);
    float scA = 32768.f / aBound, scB = 32768.f / bBound, scX = 32768.f / xBound;
    __half* ra = Ah + (size_t)n * RSH;
    __half* rb = Bh + (size_t)n * RSH;
    if (k == 0) {
      xr[n] = xv;
      ra[200] = __float2half(xv * scX);
      rb[200] = __float2half(xv * scX);
      *(float*)(ra + 220) = aBound / 32768.f;
      *(float*)(ra + 222) = xBound / 32768.f;
      *(float*)(rb + 220) = bBound / 32768.f;
      *(float*)(rb + 222) = xBound / 32768.f;
    }
    if (k < KM) {
      ra[k] = __float2half((bm + xv * wa) * scA);
      rb[k] = __float2half(xv * wb * scB);
    }
  }
}

// Edge kernel: one thread per (dst-sorted) edge. A and B rows both fp16-scaled, 448 B.
// h_k = relu(A16[dst][k]*invA + B16[src][k]*invB); gate = h@Wm2 + bm2;
// gd layout [c][e]: coalesced nontemporal dword stores.
template <int CIN>
__global__ void __launch_bounds__(256) edge_kernel(
    const int* __restrict__ srcS, const int* __restrict__ dstS,
    const __half* __restrict__ Ah, const __half* __restrict__ Bh,
    const float* __restrict__ Wm2, const float* __restrict__ bm2,
    float* __restrict__ gd) {
  int e = blockIdx.x * 256 + threadIdx.x;
  if (e >= E_EDGES) return;
  int src = srcS[e];
  int dst = dstS[e];
  const __half* Ar = Ah + (size_t)dst * RSH;
  const __half* Br = Bh + (size_t)src * RSH;
  float invA = *(const float*)(Ar + 220);
  float invB = *(const float*)(Br + 220);
  float gate[CIN];
#pragma unroll
  for (int c = 0; c < CIN; c++) gate[c] = bm2[c];
#pragma unroll 2
  for (int k = 0; k < KM; k += 8) {
    uint4 ar = *(const uint4*)(Ar + k);  // 8 fp16 of A
    uint4 br = *(const uint4*)(Br + k);  // 8 fp16 of B
    float2 a0 = h2f(ar.x), a1 = h2f(ar.y), a2 = h2f(ar.z), a3 = h2f(ar.w);
    float2 b0 = h2f(br.x), b1 = h2f(br.y), b2 = h2f(br.z), b3 = h2f(br.w);
    float h[8];
    h[0] = fmaxf(a0.x * invA + b0.x * invB, 0.f);
    h[1] = fmaxf(a0.y * invA + b0.y * invB, 0.f);
    h[2] = fmaxf(a1.x * invA + b1.x * invB, 0.f);
    h[3] = fmaxf(a1.y * invA + b1.y * invB, 0.f);
    h[4] = fmaxf(a2.x * invA + b2.x * invB, 0.f);
    h[5] = fmaxf(a2.y * invA + b2.y * invB, 0.f);
    h[6] = fmaxf(a3.x * invA + b3.x * invB, 0.f);
    h[7] = fmaxf(a3.y * invA + b3.y * invB, 0.f);
#pragma unroll
    for (int c = 0; c < CIN; c++) {
      float g = gate[c];
#pragma unroll
      for (int j = 0; j < 8; j++) g += h[j] * Wm2[(k + j) * CIN + c];
      gate[c] = g;
    }
  }
  // x-diff tails (fp16-scaled in both rows) + coalesced nontemporal stores
  float invXa = *(const float*)(Ar + 222);
  float invXb = *(const float*)(Br + 222);
  if constexpr (CIN == 20) {
    unsigned wxa[10], wxb[10];
    {
      uint4 t0 = *(const uint4*)(Ar + 200);
      uint4 t1 = *(const uint4*)(Ar + 208);
      uint2 t2 = *(const uint2*)(Ar + 216);
      wxa[0] = t0.x; wxa[1] = t0.y; wxa[2] = t0.z; wxa[3] = t0.w;
      wxa[4] = t1.x; wxa[5] = t1.y; wxa[6] = t1.z; wxa[7] = t1.w;
      wxa[8] = t2.x; wxa[9] = t2.y;
      uint4 s0 = *(const uint4*)(Br + 200);
      uint4 s1 = *(const uint4*)(Br + 208);
      uint2 s2 = *(const uint2*)(Br + 216);
      wxb[0] = s0.x; wxb[1] = s0.y; wxb[2] = s0.z; wxb[3] = s0.w;
      wxb[4] = s1.x; wxb[5] = s1.y; wxb[6] = s1.z; wxb[7] = s1.w;
      wxb[8] = s2.x; wxb[9] = s2.y;
    }
#pragma unroll
    for (int i = 0; i < 10; i++) {
      float2 fa = h2f(wxa[i]);
      float2 fb = h2f(wxb[i]);
      int c0 = 2 * i, c1 = 2 * i + 1;
      __builtin_nontemporal_store(gate[c0] * (fa.x * invXa - fb.x * invXb),
                                  gd + (size_t)c0 * E_EDGES + e);
      __builtin_nontemporal_store(gate[c1] * (fa.y * invXa - fb.y * invXb),
                                  gd + (size_t)c1 * E_EDGES + e);
    }
  } else {
    float xa = __half2float(Ar[200]) * invXa;
    float xb = __half2float(Br[200]) * invXb;
    __builtin_nontemporal_store(gate[0] * (xa - xb), gd + e);
  }
}

// afp1: after layer-d edge (gd 1-channel). Per block: 8 nodes.
//  phase1 agg; phase2 fin(1->20)+relu -> xv,xrn; phase3 prep (A,B fp16 exact-scaled).
__global__ void __launch_bounds__(256) afp1_kernel(
    const float* __restrict__ gd, const int* __restrict__ off,
    const float* __restrict__ xrp,
    const float* __restrict__ W1, const float* __restrict__ b1,
    const float* __restrict__ W2, const float* __restrict__ b2,
    const float* __restrict__ Wm1n, const float* __restrict__ bm1n,
    __half* __restrict__ Ah, __half* __restrict__ Bh, float* __restrict__ xrn) {
  __shared__ float ag[8], xp[8], degs[8];
  __shared__ float xv[8][21];
  __shared__ unsigned amaxu[8], bmaxu[8];
  __shared__ float xmaxs[8];
  int tid = threadIdx.x;
  int n0 = blockIdx.x * 8;
  if (tid < 8) {
    amaxu[tid] = 0;
    bmaxu[tid] = 0;
    int n = n0 + tid;
    int s = off[n], t = off[n + 1];
    float v = 0.f;
    for (int e = s; e < t; e++) v += gd[e];
    ag[tid] = v;
    xp[tid] = xrp[n];
    degs[tid] = (float)(t - s);
  }
  __syncthreads();
  if (tid < 160) {
    int o = tid >> 3, nl = tid & 7;
    float v = b1[o] + degs[nl] * b2[o] + ag[nl] * W2[o] + xp[nl] * W1[o];
    float r = fmaxf(v, 0.f);
    xv[nl][o] = r;
    xrn[(n0 + nl) * 20 + o] = r;
  }
  __syncthreads();
  if (tid < 8) {
    float m = 0.f;
#pragma unroll
    for (int c = 0; c < 20; c++) m = fmaxf(m, xv[tid][c]);
    xmaxs[tid] = fmaxf(m, 1e-30f);
  }
  int k = tid;
  float aa[8], bb[8];
  if (k < KM) {
    float wa[20], wb[20];
    float bm = bm1n[k];
#pragma unroll
    for (int c = 0; c < 20; c++) {
      wa[c] = Wm1n[c * KM + k];
      wb[c] = Wm1n[(20 + c) * KM + k];
    }
#pragma unroll
    for (int nl = 0; nl < 8; nl++) {
      float a = bm, b = 0.f;
#pragma unroll
      for (int c = 0; c < 20; c++) {
        a += xv[nl][c] * wa[c];
        b += xv[nl][c] * wb[c];
      }
      aa[nl] = a;
      bb[nl] = b;
    }
  }
  float mxa[8], mxb[8];
#pragma unroll
  for (int nl = 0; nl < 8; nl++) {
    mxa[nl] = (k < KM) ? fabsf(aa[nl]) : 0.f;
    mxb[nl] = (k < KM) ? fabsf(bb[nl]) : 0.f;
  }
#pragma unroll
  for (int s = 1; s < 64; s <<= 1) {
#pragma unroll
    for (int nl = 0; nl < 8; nl++) {
      mxa[nl] = fmaxf(mxa[nl], __shfl_xor(mxa[nl], s));
      mxb[nl] = fmaxf(mxb[nl], __shfl_xor(mxb[nl], s));
    }
  }
  if ((tid & 63) == 0) {
#pragma unroll
    for (int nl = 0; nl < 8; nl++) {
      atomicMax(&amaxu[nl], __float_as_uint(mxa[nl]));
      atomicMax(&bmaxu[nl], __float_as_uint(mxb[nl]));
    }
  }
  __syncthreads();
  if (k < KM) {
#pragma unroll
    for (int nl = 0; nl < 8; nl++) {
      float amax = fmaxf(__uint_as_float(amaxu[nl]), 1e-30f);
      float bmax = fmaxf(__uint_as_float(bmaxu[nl]), 1e-30f);
      float xmax = xmaxs[nl];
      __half* ra = Ah + (size_t)(n0 + nl) * RSH;
      __half* rb = Bh + (size_t)(n0 + nl) * RSH;
      ra[k] = __float2half(aa[nl] * (32768.f / amax));
      rb[k] = __float2half(bb[nl] * (32768.f / bmax));
      if (k < 20) {
        __half xh = __float2half(xv[nl][k] * (32768.f / xmax));
        ra[200 + k] = xh;
        rb[200 + k] = xh;
      }
      if (k == 0) {
        *(float*)(ra + 220) = amax / 32768.f;
        *(float*)(ra + 222) = xmax / 32768.f;
        *(float*)(rb + 220) = bmax / 32768.f;
        *(float*)(rb + 222) = xmax / 32768.f;
      }
    }
  }
}

// afp20: after a hidden edge (gd 20-channel). Same 3 phases, CIN=20.
__global__ void __launch_bounds__(256) afp20_kernel(
    const float* __restrict__ gd, const int* __restrict__ off,
    const float* __restrict__ xrp,
    const float* __restrict__ W1, const float* __restrict__ b1,
    const float* __restrict__ W2, const float* __restrict__ b2,
    const float* __restrict__ Wm1n, const float* __restrict__ bm1n,
    __half* __restrict__ Ah, __half* __restrict__ Bh, float* __restrict__ xrn) {
  __shared__ float ag[8][21], xp[8][21], xv[8][21], degs[8];
  __shared__ unsigned amaxu[8], bmaxu[8];
  __shared__ float xmaxs[8];
  int tid = threadIdx.x;
  int n0 = blockIdx.x * 8;
  if (tid < 8) { amaxu[tid] = 0; bmaxu[tid] = 0; }
  if (tid < 160) {
    int c = tid >> 3, nl = tid & 7;  // adjacent lanes: same c, adjacent n
    int n = n0 + nl;
    int s = off[n], t = off[n + 1];
    const float* g = gd + (size_t)c * E_EDGES;
    float v = 0.f;
    for (int e = s; e < t; e++) v += g[e];
    ag[nl][c] = v;
    xp[nl][c] = xrp[n * 20 + c];
    if (c == 0) degs[nl] = (float)(t - s);
  }
  __syncthreads();
  if (tid < 160) {
    int o = tid >> 3, nl = tid & 7;
    float v = b1[o] + degs[nl] * b2[o];
#pragma unroll
    for (int c = 0; c < 20; c++) {
      v += ag[nl][c] * W2[c * 20 + o] + xp[nl][c] * W1[c * 20 + o];
    }
    float r = fmaxf(v, 0.f);
    xv[nl][o] = r;
    xrn[(n0 + nl) * 20 + o] = r;
  }
  __syncthreads();
  if (tid < 8) {
    float m = 0.f;
#pragma unroll
    for (int c = 0; c < 20; c++) m = fmaxf(m, xv[tid][c]);
    xmaxs[tid] = fmaxf(m, 1e-30f);
  }
  int k = tid;
  float aa[8], bb[8];
  if (k < KM) {
    float wa[20], wb[20];
    float bm = bm1n[k];
#pragma unroll
    for (int c = 0; c < 20; c++) {
      wa[c] = Wm1n[c * KM + k];
      wb[c] = Wm1n[(20 + c) * KM + k];
    }
#pragma unroll
    for (int nl = 0; nl < 8; nl++) {
      float a = bm, b = 0.f;
#pragma unroll
      for (int c = 0; c < 20; c++) {
        a += xv[nl][c] * wa[c];
        b += xv[nl][c] * wb[c];
      }
      aa[nl] = a;
      bb[nl] = b;
    }
  }
  float mxa[8], mxb[8];
#pragma unroll
  for (int nl = 0; nl < 8; nl++) {
    mxa[nl] = (k < KM) ? fabsf(aa[nl]) : 0.f;
    mxb[nl] = (k < KM) ? fabsf(bb[nl]) : 0.f;
  }
#pragma unroll
  for (int s = 1; s < 64; s <<= 1) {
#pragma unroll
    for (int nl = 0; nl < 8; nl++) {
      mxa[nl] = fmaxf(mxa[nl], __shfl_xor(mxa[nl], s));
      mxb[nl] = fmaxf(mxb[nl], __shfl_xor(mxb[nl], s));
    }
  }
  if ((tid & 63) == 0) {
#pragma unroll
    for (int nl = 0; nl < 8; nl++) {
      atomicMax(&amaxu[nl], __float_as_uint(mxa[nl]));
      atomicMax(&bmaxu[nl], __float_as_uint(mxb[nl]));
    }
  }
  __syncthreads();
  if (k < KM) {
#pragma unroll
    for (int nl = 0; nl < 8; nl++) {
      float amax = fmaxf(__uint_as_float(amaxu[nl]), 1e-30f);
      float bmax = fmaxf(__uint_as_float(bmaxu[nl]), 1e-30f);
      float xmax = xmaxs[nl];
      __half* ra = Ah + (size_t)(n0 + nl) * RSH;
      __half* rb = Bh + (size_t)(n0 + nl) * RSH;
      ra[k] = __float2half(aa[nl] * (32768.f / amax));
      rb[k] = __float2half(bb[nl] * (32768.f / bmax));
      if (k < 20) {
        __half xh = __float2half(xv[nl][k] * (32768.f / xmax));
        ra[200 + k] = xh;
        rb[200 + k] = xh;
      }
      if (k == 0) {
        *(float*)(ra + 220) = amax / 32768.f;
        *(float*)(ra + 222) = xmax / 32768.f;
        *(float*)(rb + 220) = bmax / 32768.f;
        *(float*)(rb + 222) = xmax / 32768.f;
      }
    }
  }
}

// final: agg(20ch) + fin(20->1), no relu, writes d_out.
__global__ void __launch_bounds__(256) aggfin_out_kernel(
    const float* __restrict__ gd, const int* __restrict__ off,
    const float* __restrict__ xrp,
    const float* __restrict__ W1, const float* __restrict__ b1,
    const float* __restrict__ W2, const float* __restrict__ b2,
    float* __restrict__ out) {
  __shared__ float ag[8][21], xp[8][21], degs[8];
  int tid = threadIdx.x;
  int n0 = blockIdx.x * 8;
  if (tid < 160) {
    int c = tid >> 3, nl = tid & 7;
    int n = n0 + nl;
    int s = off[n], t = off[n + 1];
    const float* g = gd + (size_t)c * E_EDGES;
    float v = 0.f;
    for (int e = s; e < t; e++) v += g[e];
    ag[nl][c] = v;
    xp[nl][c] = xrp[n * 20 + c];
    if (c == 0) degs[nl] = (float)(t - s);
  }
  __syncthreads();
  if (tid < 8) {
    float v = b1[0] + degs[tid] * b2[0];
#pragma unroll
    for (int c = 0; c < 20; c++) {
      v += ag[tid][c] * W2[c] + xp[tid][c] * W1[c];
    }
    out[n0 + tid] = v;
  }
}

// ---------------- launch ----------------

extern "C" void kernel_launch(void* const* d_in, const int* in_sizes, int n_in,
                              void* d_out, int out_size, void* d_ws, size_t ws_size,
                              hipStream_t stream) {
  const float* features = (const float*)d_in[0];
  const int* edges = (const int*)d_in[1];
  // d_in[2] = weights (unused by reference)

  const float *dW1 = (const float*)d_in[3], *db1 = (const float*)d_in[4],
              *dWm1 = (const float*)d_in[5], *dbm1 = (const float*)d_in[6],
              *dWm2 = (const float*)d_in[7], *dbm2 = (const float*)d_in[8],
              *dW2 = (const float*)d_in[9], *db2 = (const float*)d_in[10];
  const float *hW1 = (const float*)d_in[11], *hb1 = (const float*)d_in[12],
              *hWm1 = (const float*)d_in[13], *hbm1 = (const float*)d_in[14],
              *hWm2 = (const float*)d_in[15], *hbm2 = (const float*)d_in[16],
              *hW2 = (const float*)d_in[17], *hb2 = (const float*)d_in[18];
  const float *oW1 = (const float*)d_in[19], *ob1 = (const float*)d_in[20],
              *oWm1 = (const float*)d_in[21], *obm1 = (const float*)d_in[22],
              *oWm2 = (const float*)d_in[23], *obm2 = (const float*)d_in[24],
              *oW2 = (const float*)d_in[25], *ob2 = (const float*)d_in[26];

  // workspace layout (float units)
  float* fws = (float*)d_ws;
  size_t o = 0;
  __half* Ah = (__half*)(fws + o); o += (size_t)N_NODES * RSH / 2;  // 2.8M floats
  __half* Bh = (__half*)(fws + o); o += (size_t)N_NODES * RSH / 2;  // 2.8M floats
  float* gd = fws + o;    o += (size_t)20 * E_EDGES;       // 8.0M  ([c][e])
  float* xrA = fws + o;   o += (size_t)N_NODES * 20;
  float* xrB = fws + o;   o += (size_t)N_NODES * 20;
  int* ip = (int*)(fws + o);
  int* hist = ip;   ip += N_NODES;
  int* off = ip;    ip += N_NODES + 4;
  int* cursor = ip; ip += N_NODES;
  int* srcS = ip;   ip += E_EDGES;
  int* dstS = ip;   ip += E_EDGES;

  const int B256 = 256;
  const int EDGE_G = (E_EDGES + B256 - 1) / B256;  // 1563
  const int NODE8_G = N_NODES / 8;  // 3125, exact

  // build dst-sorted edge list + CSR offsets (recomputed every launch)
  (void)hipMemsetAsync(hist, 0, N_NODES * sizeof(int), stream);
  hist_kernel<<<EDGE_G, B256, 0, stream>>>(edges, hist);
  scan_kernel<<<1, 1024, 0, stream>>>(hist, off, cursor);
  scatter_kernel<<<EDGE_G, B256, 0, stream>>>(edges, cursor, srcS, dstS);

  // layer d: 1 -> 20
  prep_d_kernel<<<NODE8_G, B256, 0, stream>>>(features, dWm1, dbm1, Ah, Bh, xrA);
  edge_kernel<1><<<EDGE_G, B256, 0, stream>>>(srcS, dstS, Ah, Bh, dWm2, dbm2, gd);
  afp1_kernel<<<NODE8_G, B256, 0, stream>>>(gd, off, xrA, dW1, db1, dW2, db2,
                                            hWm1, hbm1, Ah, Bh, xrB);

  // hidden1
  edge_kernel<20><<<EDGE_G, B256, 0, stream>>>(srcS, dstS, Ah, Bh, hWm2, hbm2, gd);
  afp20_kernel<<<NODE8_G, B256, 0, stream>>>(gd, off, xrB, hW1, hb1, hW2, hb2,
                                             hWm1, hbm1, Ah, Bh, xrA);
  // hidden2
  edge_kernel<20><<<EDGE_G, B256, 0, stream>>>(srcS, dstS, Ah, Bh, hWm2, hbm2, gd);
  afp20_kernel<<<NODE8_G, B256, 0, stream>>>(gd, off, xrA, hW1, hb1, hW2, hb2,
                                             hWm1, hbm1, Ah, Bh, xrB);
  // hidden3 -> preps output layer (oWm1)
  edge_kernel<20><<<EDGE_G, B256, 0, stream>>>(srcS, dstS, Ah, Bh, hWm2, hbm2, gd);
  afp20_kernel<<<NODE8_G, B256, 0, stream>>>(gd, off, xrB, hW1, hb1, hW2, hb2,
                                             oWm1, obm1, Ah, Bh, xrA);
  // output layer: 20 -> 1 (no trailing relu)
  edge_kernel<20><<<EDGE_G, B256, 0, stream>>>(srcS, dstS, Ah, Bh, oWm2, obm2, gd);
  aggfin_out_kernel<<<NODE8_G, B256, 0, stream>>>(gd, off, xrA, oW1, ob1, oW2, ob2,
                                                  (float*)d_out);
}

// Round 13
// 789.504 us; speedup vs baseline: 1.0710x; 1.0710x over previous
//
#include <hip/hip_runtime.h>
#include <hip/hip_fp16.h>

#define N_NODES 25000   // = 3125 * 8 exactly
#define E_EDGES 400000
#define KM 200     // message channels
#define RS 224     // A-row stride (floats): 200 fp32 A | 20 fp32 x | pad (896 B)
#define RSBH 224   // B-row stride (halfs): 200 fp16 B | 20 fp16 x | fp32 inv_p | fp32 inv_x (448 B)

__device__ __forceinline__ float2 h2f(unsigned u) {
  return __half22float2(*(const __half2*)&u);
}

// ---------------- sort-by-dst (CSR build) ----------------

__global__ void hist_kernel(const int* __restrict__ edges, int* __restrict__ hist) {
  int e = blockIdx.x * blockDim.x + threadIdx.x;
  if (e < E_EDGES) atomicAdd(&hist[edges[E_EDGES + e]], 1);
}

__global__ void scan_kernel(const int* __restrict__ hist, int* __restrict__ off,
                            int* __restrict__ cursor) {
  __shared__ int sums[1024];
  const int CH = (N_NODES + 1023) / 1024;  // 25
  int tid = threadIdx.x;
  int base = tid * CH;
  int s = 0;
  for (int i = 0; i < CH; i++) {
    int idx = base + i;
    if (idx < N_NODES) s += hist[idx];
  }
  sums[tid] = s;
  __syncthreads();
  for (int d = 1; d < 1024; d <<= 1) {
    int v = (tid >= d) ? sums[tid - d] : 0;
    __syncthreads();
    sums[tid] += v;
    __syncthreads();
  }
  int run = (tid == 0) ? 0 : sums[tid - 1];
  for (int i = 0; i < CH; i++) {
    int idx = base + i;
    if (idx < N_NODES) {
      off[idx] = run;
      cursor[idx] = run;
      run += hist[idx];
    }
  }
  if (tid == 1023) off[N_NODES] = run;  // == E
}

__global__ void scatter_kernel(const int* __restrict__ edges, int* __restrict__ cursor,
                               int2* __restrict__ se) {
  int e = blockIdx.x * blockDim.x + threadIdx.x;
  if (e < E_EDGES) {
    int s = edges[e];
    int d = edges[E_EDGES + e];
    int pos = atomicAdd(&cursor[d], 1);
    se[pos] = make_int2(s, d);
  }
}

// ---------------- per-layer kernels ----------------

// prep (layer d, CIN=1): A fp32; B fp16 (bound-based scales); x-tail fp16 in B.
__global__ void __launch_bounds__(256) prep_d_kernel(
    const float* __restrict__ xin,
    const float* __restrict__ Wm1, const float* __restrict__ bm1,
    float* __restrict__ A2, __half* __restrict__ Bh, float* __restrict__ xr) {
  __shared__ unsigned wbmaxu;
  int k = threadIdx.x;  // 0..255
  if (k == 0) wbmaxu = 0;
  __syncthreads();
  float wa = 0.f, wb = 0.f, bm = 0.f;
  if (k < KM) {
    bm = bm1[k];
    wa = Wm1[k];
    wb = Wm1[KM + k];
  }
  float mb = (k < KM) ? fabsf(wb) : 0.f;
#pragma unroll
  for (int s = 1; s < 64; s <<= 1) mb = fmaxf(mb, __shfl_xor(mb, s));
  if ((k & 63) == 0) atomicMax(&wbmaxu, __float_as_uint(mb));
  __syncthreads();
  float wbmax = fmaxf(__uint_as_float(wbmaxu), 1e-30f);
  int n0 = blockIdx.x * 8;
  for (int i = 0; i < 8; i++) {
    int n = n0 + i;
    float xv = xin[n];
    float bBound = fmaxf(fabsf(xv) * wbmax, 1e-30f);
    float xBound = fmaxf(fabsf(xv), 1e-30f);
    size_t rowA = (size_t)n * RS;
    __half* rb = Bh + (size_t)n * RSBH;
    if (k == 0) {
      xr[n] = xv;
      A2[rowA + KM] = xv;
      rb[200] = __float2half(xv * (32768.f / xBound));
      *(float*)(rb + 220) = bBound / 32768.f;
      *(float*)(rb + 222) = xBound / 32768.f;
    }
    if (k < KM) {
      A2[rowA + k] = bm + xv * wa;
      rb[k] = __float2half(xv * wb * (32768.f / bBound));
    }
  }
}

// Edge kernel: one thread per (dst-sorted) edge. A fp32 (dst-shared, streamed),
// B fp16 448 B (randomly gathered — the HBM-duplication term).
// h_k = relu(A[dst][k] + B16[src][k]*invB); gate = h@Wm2 + bm2;
// gd layout [c][e]: coalesced nontemporal dword stores.
template <int CIN>
__global__ void __launch_bounds__(256) edge_kernel(
    const int2* __restrict__ se,
    const float* __restrict__ A2, const __half* __restrict__ Bh,
    const float* __restrict__ Wm2, const float* __restrict__ bm2,
    float* __restrict__ gd) {
  int e = blockIdx.x * 256 + threadIdx.x;
  if (e >= E_EDGES) return;
  int2 sd = se[e];
  int src = sd.x;
  int dst = sd.y;
  const float* Ar = A2 + (size_t)dst * RS;
  const __half* Br = Bh + (size_t)src * RSBH;
  float invB = *(const float*)(Br + 220);
  float gate[CIN];
#pragma unroll
  for (int c = 0; c < CIN; c++) gate[c] = bm2[c];
#pragma unroll 2
  for (int k = 0; k < KM; k += 8) {
    float4 a0 = *(const float4*)(Ar + k);
    float4 a1 = *(const float4*)(Ar + k + 4);
    uint4 braw = *(const uint4*)(Br + k);  // 8 fp16
    float2 f0 = h2f(braw.x), f1 = h2f(braw.y), f2 = h2f(braw.z), f3 = h2f(braw.w);
    float h[8];
    h[0] = fmaxf(a0.x + f0.x * invB, 0.f);
    h[1] = fmaxf(a0.y + f0.y * invB, 0.f);
    h[2] = fmaxf(a0.z + f1.x * invB, 0.f);
    h[3] = fmaxf(a0.w + f1.y * invB, 0.f);
    h[4] = fmaxf(a1.x + f2.x * invB, 0.f);
    h[5] = fmaxf(a1.y + f2.y * invB, 0.f);
    h[6] = fmaxf(a1.z + f3.x * invB, 0.f);
    h[7] = fmaxf(a1.w + f3.y * invB, 0.f);
#pragma unroll
    for (int c = 0; c < CIN; c++) {
      float g = gate[c];
#pragma unroll
      for (int j = 0; j < 8; j++) g += h[j] * Wm2[(k + j) * CIN + c];
      gate[c] = g;
    }
  }
  // x-diff tails: A fp32, B fp16-scaled; coalesced nontemporal stores
  float invXb = *(const float*)(Br + 222);
  if constexpr (CIN == 20) {
    unsigned wxb[10];
    {
      uint4 s0 = *(const uint4*)(Br + 200);
      uint4 s1 = *(const uint4*)(Br + 208);
      uint2 s2 = *(const uint2*)(Br + 216);
      wxb[0] = s0.x; wxb[1] = s0.y; wxb[2] = s0.z; wxb[3] = s0.w;
      wxb[4] = s1.x; wxb[5] = s1.y; wxb[6] = s1.z; wxb[7] = s1.w;
      wxb[8] = s2.x; wxb[9] = s2.y;
    }
#pragma unroll
    for (int i = 0; i < 10; i++) {
      float2 xa = *(const float2*)(Ar + KM + 2 * i);
      float2 fb = h2f(wxb[i]);
      int c0 = 2 * i, c1 = 2 * i + 1;
      __builtin_nontemporal_store(gate[c0] * (xa.x - fb.x * invXb),
                                  gd + (size_t)c0 * E_EDGES + e);
      __builtin_nontemporal_store(gate[c1] * (xa.y - fb.y * invXb),
                                  gd + (size_t)c1 * E_EDGES + e);
    }
  } else {
    float xa = Ar[KM];
    float xb = __half2float(Br[200]) * invXb;
    __builtin_nontemporal_store(gate[0] * (xa - xb), gd + e);
  }
}

// afp1: after layer-d edge (gd 1-channel). Per block: 8 nodes.
//  phase1 agg; phase2 fin(1->20)+relu -> xv,xrn; phase3 prep (A fp32, B fp16 exact-scaled).
__global__ void __launch_bounds__(256) afp1_kernel(
    const float* __restrict__ gd, const int* __restrict__ off,
    const float* __restrict__ xrp,
    const float* __restrict__ W1, const float* __restrict__ b1,
    const float* __restrict__ W2, const float* __restrict__ b2,
    const float* __restrict__ Wm1n, const float* __restrict__ bm1n,
    float* __restrict__ A2, __half* __restrict__ Bh, float* __restrict__ xrn) {
  __shared__ float ag[8], xp[8], degs[8];
  __shared__ float xv[8][21];
  __shared__ unsigned bmaxu[8];
  __shared__ float xmaxs[8];
  int tid = threadIdx.x;
  int n0 = blockIdx.x * 8;
  if (tid < 8) {
    bmaxu[tid] = 0;
    int n = n0 + tid;
    int s = off[n], t = off[n + 1];
    float v = 0.f;
    for (int e = s; e < t; e++) v += gd[e];
    ag[tid] = v;
    xp[tid] = xrp[n];
    degs[tid] = (float)(t - s);
  }
  __syncthreads();
  if (tid < 160) {
    int o = tid >> 3, nl = tid & 7;
    float v = b1[o] + degs[nl] * b2[o] + ag[nl] * W2[o] + xp[nl] * W1[o];
    float r = fmaxf(v, 0.f);
    xv[nl][o] = r;
    xrn[(n0 + nl) * 20 + o] = r;
  }
  __syncthreads();
  if (tid < 8) {
    float m = 0.f;
#pragma unroll
    for (int c = 0; c < 20; c++) m = fmaxf(m, xv[tid][c]);
    xmaxs[tid] = fmaxf(m, 1e-30f);
  }
  int k = tid;
  float aa[8], bb[8];
  if (k < KM) {
    float wa[20], wb[20];
    float bm = bm1n[k];
#pragma unroll
    for (int c = 0; c < 20; c++) {
      wa[c] = Wm1n[c * KM + k];
      wb[c] = Wm1n[(20 + c) * KM + k];
    }
#pragma unroll
    for (int nl = 0; nl < 8; nl++) {
      float a = bm, b = 0.f;
#pragma unroll
      for (int c = 0; c < 20; c++) {
        a += xv[nl][c] * wa[c];
        b += xv[nl][c] * wb[c];
      }
      aa[nl] = a;
      bb[nl] = b;
    }
  }
  float mxb[8];
#pragma unroll
  for (int nl = 0; nl < 8; nl++) mxb[nl] = (k < KM) ? fabsf(bb[nl]) : 0.f;
#pragma unroll
  for (int s = 1; s < 64; s <<= 1) {
#pragma unroll
    for (int nl = 0; nl < 8; nl++) mxb[nl] = fmaxf(mxb[nl], __shfl_xor(mxb[nl], s));
  }
  if ((tid & 63) == 0) {
#pragma unroll
    for (int nl = 0; nl < 8; nl++) atomicMax(&bmaxu[nl], __float_as_uint(mxb[nl]));
  }
  __syncthreads();
  if (k < KM) {
#pragma unroll
    for (int nl = 0; nl < 8; nl++) {
      float bmax = fmaxf(__uint_as_float(bmaxu[nl]), 1e-30f);
      float xmax = xmaxs[nl];
      size_t rowA = (size_t)(n0 + nl) * RS;
      __half* rb = Bh + (size_t)(n0 + nl) * RSBH;
      A2[rowA + k] = aa[nl];
      rb[k] = __float2half(bb[nl] * (32768.f / bmax));
      if (k < 20) {
        A2[rowA + KM + k] = xv[nl][k];
        rb[200 + k] = __float2half(xv[nl][k] * (32768.f / xmax));
      }
      if (k == 0) {
        *(float*)(rb + 220) = bmax / 32768.f;
        *(float*)(rb + 222) = xmax / 32768.f;
      }
    }
  }
}

// afp20: after a hidden edge (gd 20-channel). Same 3 phases, CIN=20.
__global__ void __launch_bounds__(256) afp20_kernel(
    const float* __restrict__ gd, const int* __restrict__ off,
    const float* __restrict__ xrp,
    const float* __restrict__ W1, const float* __restrict__ b1,
    const float* __restrict__ W2, const float* __restrict__ b2,
    const float* __restrict__ Wm1n, const float* __restrict__ bm1n,
    float* __restrict__ A2, __half* __restrict__ Bh, float* __restrict__ xrn) {
  __shared__ float ag[8][21], xp[8][21], xv[8][21], degs[8];
  __shared__ unsigned bmaxu[8];
  __shared__ float xmaxs[8];
  int tid = threadIdx.x;
  int n0 = blockIdx.x * 8;
  if (tid < 8) bmaxu[tid] = 0;
  if (tid < 160) {
    int c = tid >> 3, nl = tid & 7;  // adjacent lanes: same c, adjacent n
    int n = n0 + nl;
    int s = off[n], t = off[n + 1];
    const float* g = gd + (size_t)c * E_EDGES;
    float v = 0.f;
    for (int e = s; e < t; e++) v += g[e];
    ag[nl][c] = v;
    xp[nl][c] = xrp[n * 20 + c];
    if (c == 0) degs[nl] = (float)(t - s);
  }
  __syncthreads();
  if (tid < 160) {
    int o = tid >> 3, nl = tid & 7;
    float v = b1[o] + degs[nl] * b2[o];
#pragma unroll
    for (int c = 0; c < 20; c++) {
      v += ag[nl][c] * W2[c * 20 + o] + xp[nl][c] * W1[c * 20 + o];
    }
    float r = fmaxf(v, 0.f);
    xv[nl][o] = r;
    xrn[(n0 + nl) * 20 + o] = r;
  }
  __syncthreads();
  if (tid < 8) {
    float m = 0.f;
#pragma unroll
    for (int c = 0; c < 20; c++) m = fmaxf(m, xv[tid][c]);
    xmaxs[tid] = fmaxf(m, 1e-30f);
  }
  int k = tid;
  float aa[8], bb[8];
  if (k < KM) {
    float wa[20], wb[20];
    float bm = bm1n[k];
#pragma unroll
    for (int c = 0; c < 20; c++) {
      wa[c] = Wm1n[c * KM + k];
      wb[c] = Wm1n[(20 + c) * KM + k];
    }
#pragma unroll
    for (int nl = 0; nl < 8; nl++) {
      float a = bm, b = 0.f;
#pragma unroll
      for (int c = 0; c < 20; c++) {
        a += xv[nl][c] * wa[c];
        b += xv[nl][c] * wb[c];
      }
      aa[nl] = a;
      bb[nl] = b;
    }
  }
  float mxb[8];
#pragma unroll
  for (int nl = 0; nl < 8; nl++) mxb[nl] = (k < KM) ? fabsf(bb[nl]) : 0.f;
#pragma unroll
  for (int s = 1; s < 64; s <<= 1) {
#pragma unroll
    for (int nl = 0; nl < 8; nl++) mxb[nl] = fmaxf(mxb[nl], __shfl_xor(mxb[nl], s));
  }
  if ((tid & 63) == 0) {
#pragma unroll
    for (int nl = 0; nl < 8; nl++) atomicMax(&bmaxu[nl], __float_as_uint(mxb[nl]));
  }
  __syncthreads();
  if (k < KM) {
#pragma unroll
    for (int nl = 0; nl < 8; nl++) {
      float bmax = fmaxf(__uint_as_float(bmaxu[nl]), 1e-30f);
      float xmax = xmaxs[nl];
      size_t rowA = (size_t)(n0 + nl) * RS;
      __half* rb = Bh + (size_t)(n0 + nl) * RSBH;
      A2[rowA + k] = aa[nl];
      rb[k] = __float2half(bb[nl] * (32768.f / bmax));
      if (k < 20) {
        A2[rowA + KM + k] = xv[nl][k];
        rb[200 + k] = __float2half(xv[nl][k] * (32768.f / xmax));
      }
      if (k == 0) {
        *(float*)(rb + 220) = bmax / 32768.f;
        *(float*)(rb + 222) = xmax / 32768.f;
      }
    }
  }
}

// final: agg(20ch) + fin(20->1), no relu, writes d_out.
__global__ void __launch_bounds__(256) aggfin_out_kernel(
    const float* __restrict__ gd, const int* __restrict__ off,
    const float* __restrict__ xrp,
    const float* __restrict__ W1, const float* __restrict__ b1,
    const float* __restrict__ W2, const float* __restrict__ b2,
    float* __restrict__ out) {
  __shared__ float ag[8][21], xp[8][21], degs[8];
  int tid = threadIdx.x;
  int n0 = blockIdx.x * 8;
  if (tid < 160) {
    int c = tid >> 3, nl = tid & 7;
    int n = n0 + nl;
    int s = off[n], t = off[n + 1];
    const float* g = gd + (size_t)c * E_EDGES;
    float v = 0.f;
    for (int e = s; e < t; e++) v += g[e];
    ag[nl][c] = v;
    xp[nl][c] = xrp[n * 20 + c];
    if (c == 0) degs[nl] = (float)(t - s);
  }
  __syncthreads();
  if (tid < 8) {
    float v = b1[0] + degs[tid] * b2[0];
#pragma unroll
    for (int c = 0; c < 20; c++) {
      v += ag[tid][c] * W2[c] + xp[tid][c] * W1[c];
    }
    out[n0 + tid] = v;
  }
}

// ---------------- launch ----------------

extern "C" void kernel_launch(void* const* d_in, const int* in_sizes, int n_in,
                              void* d_out, int out_size, void* d_ws, size_t ws_size,
                              hipStream_t stream) {
  const float* features = (const float*)d_in[0];
  const int* edges = (const int*)d_in[1];
  // d_in[2] = weights (unused by reference)

  const float *dW1 = (const float*)d_in[3], *db1 = (const float*)d_in[4],
              *dWm1 = (const float*)d_in[5], *dbm1 = (const float*)d_in[6],
              *dWm2 = (const float*)d_in[7], *dbm2 = (const float*)d_in[8],
              *dW2 = (const float*)d_in[9], *db2 = (const float*)d_in[10];
  const float *hW1 = (const float*)d_in[11], *hb1 = (const float*)d_in[12],
              *hWm1 = (const float*)d_in[13], *hbm1 = (const float*)d_in[14],
              *hWm2 = (const float*)d_in[15], *hbm2 = (const float*)d_in[16],
              *hW2 = (const float*)d_in[17], *hb2 = (const float*)d_in[18];
  const float *oW1 = (const float*)d_in[19], *ob1 = (const float*)d_in[20],
              *oWm1 = (const float*)d_in[21], *obm1 = (const float*)d_in[22],
              *oWm2 = (const float*)d_in[23], *obm2 = (const float*)d_in[24],
              *oW2 = (const float*)d_in[25], *ob2 = (const float*)d_in[26];

  // workspace layout (float units)
  float* fws = (float*)d_ws;
  size_t o = 0;
  float* A2 = fws + o;             o += (size_t)N_NODES * RS;        // 5.6M
  __half* Bh = (__half*)(fws + o); o += (size_t)N_NODES * RSBH / 2;  // 2.8M floats
  float* gd = fws + o;             o += (size_t)20 * E_EDGES;        // 8.0M ([c][e])
  float* xrA = fws + o;            o += (size_t)N_NODES * 20;
  float* xrB = fws + o;            o += (size_t)N_NODES * 20;
  int* ip = (int*)(fws + o);
  int* hist = ip;   ip += N_NODES;
  int* off = ip;    ip += N_NODES + 4;
  int* cursor = ip; ip += N_NODES;
  int2* se = (int2*)ip;

  const int B256 = 256;
  const int EDGE_G = (E_EDGES + B256 - 1) / B256;  // 1563
  const int NODE8_G = N_NODES / 8;  // 3125, exact

  // build dst-sorted edge list + CSR offsets (recomputed every launch)
  (void)hipMemsetAsync(hist, 0, N_NODES * sizeof(int), stream);
  hist_kernel<<<EDGE_G, B256, 0, stream>>>(edges, hist);
  scan_kernel<<<1, 1024, 0, stream>>>(hist, off, cursor);
  scatter_kernel<<<EDGE_G, B256, 0, stream>>>(edges, cursor, se);

  // layer d: 1 -> 20
  prep_d_kernel<<<NODE8_G, B256, 0, stream>>>(features, dWm1, dbm1, A2, Bh, xrA);
  edge_kernel<1><<<EDGE_G, B256, 0, stream>>>(se, A2, Bh, dWm2, dbm2, gd);
  afp1_kernel<<<NODE8_G, B256, 0, stream>>>(gd, off, xrA, dW1, db1, dW2, db2,
                                            hWm1, hbm1, A2, Bh, xrB);

  // hidden1
  edge_kernel<20><<<EDGE_G, B256, 0, stream>>>(se, A2, Bh, hWm2, hbm2, gd);
  afp20_kernel<<<NODE8_G, B256, 0, stream>>>(gd, off, xrB, hW1, hb1, hW2, hb2,
                                             hWm1, hbm1, A2, Bh, xrA);
  // hidden2
  edge_kernel<20><<<EDGE_G, B256, 0, stream>>>(se, A2, Bh, hWm2, hbm2, gd);
  afp20_kernel<<<NODE8_G, B256, 0, stream>>>(gd, off, xrA, hW1, hb1, hW2, hb2,
                                             hWm1, hbm1, A2, Bh, xrB);
  // hidden3 -> preps output layer (oWm1)
  edge_kernel<20><<<EDGE_G, B256, 0, stream>>>(se, A2, Bh, hWm2, hbm2, gd);
  afp20_kernel<<<NODE8_G, B256, 0, stream>>>(gd, off, xrB, hW1, hb1, hW2, hb2,
                                             oWm1, obm1, A2, Bh, xrA);
  // output layer: 20 -> 1 (no trailing relu)
  edge_kernel<20><<<EDGE_G, B256, 0, stream>>>(se, A2, Bh, oWm2, obm2, gd);
  aggfin_out_kernel<<<NODE8_G, B256, 0, stream>>>(gd, off, xrA, oW1, ob1, oW2, ob2,
                                                  (float*)d_out);
}